// Round 1
// baseline (292.986 us; speedup 1.0000x reference)
//
#include <hip/hip_runtime.h>
#include <stdint.h>
#include <stddef.h>

#define BB 4
#define CC 128
#define HWN 4096

typedef __bf16 bf16x4 __attribute__((ext_vector_type(4)));
typedef __bf16 bf16x8 __attribute__((ext_vector_type(8)));
typedef float f32x4 __attribute__((ext_vector_type(4)));

union BF8 { bf16x8 v; bf16x4 h[2]; };

__device__ __forceinline__ void g2l16(void* lds_ptr, const void* gptr) {
  __builtin_amdgcn_global_load_lds(
      (const __attribute__((address_space(1))) uint32_t*)gptr,
      (__attribute__((address_space(3))) uint32_t*)lds_ptr,
      16, 0, 0);
}

// ---------------- per-(b,c) mean/rstd over HW (unbiased var, +eps) -------------
__global__ __launch_bounds__(256) void moments_kernel(
    const float* __restrict__ content, const float* __restrict__ guidance,
    float2* __restrict__ mom) {
  int row = blockIdx.x;  // b*C + c
  const float* x = (blockIdx.y ? guidance : content) + (size_t)row * HWN;
  int tid = threadIdx.x;
  float s1 = 0.f, s2 = 0.f;
#pragma unroll
  for (int i = 0; i < 16; ++i) {
    float v = x[tid + i * 256];
    s1 += v; s2 += v * v;
  }
#pragma unroll
  for (int off = 32; off > 0; off >>= 1) {
    s1 += __shfl_down(s1, off);
    s2 += __shfl_down(s2, off);
  }
  __shared__ float r1[4], r2[4];
  int wid = tid >> 6;
  if ((tid & 63) == 0) { r1[wid] = s1; r2[wid] = s2; }
  __syncthreads();
  if (tid == 0) {
    float t1 = r1[0] + r1[1] + r1[2] + r1[3];
    float t2 = r2[0] + r2[1] + r2[2] + r2[3];
    float mean = t1 * (1.f / HWN);
    float var = (t2 - (float)HWN * mean * mean) * (1.f / (HWN - 1));
    mom[blockIdx.y * (BB * CC) + row] = make_float2(mean, rsqrtf(var + 1e-5f));
  }
}

// ---------------- 1x1 conv (optionally mvn-normalized input), f32 ---------------
// mode 0: G1 = g1w@mvn(content)+b  -> G1 f32 [b][c][p] + KT bf16 [b][p][c]
// mode 1: Fm = fw@mvn(guidance)+b  -> Qb bf16 [b][c][p]
// mode 2: Hm = hw@guidance+b       -> Vb bf16 [b][c][p]
// mode 3: T  = outw@G1             -> Tf f32  [b][c][p]
__global__ __launch_bounds__(256) void conv_kernel(
    const float* __restrict__ content, const float* __restrict__ guidance,
    const float* __restrict__ G1in,
    const float* __restrict__ g1w, const float* __restrict__ g1b,
    const float* __restrict__ fw, const float* __restrict__ fb,
    const float* __restrict__ hwt, const float* __restrict__ hb,
    const float* __restrict__ outw,
    const float2* __restrict__ mom,
    float* __restrict__ G1, float* __restrict__ Tf,
    __bf16* __restrict__ Qb, __bf16* __restrict__ KTb, __bf16* __restrict__ Vb,
    int zbase) {
  int mode = blockIdx.z + zbase;
  int b = blockIdx.y;
  int p = blockIdx.x * 64 + (threadIdx.x & 63);
  int wid = threadIdx.x >> 6;
  const float* x; const float* w; const float* bias; const float2* mm;
  if (mode == 0)      { x = content;  w = g1w;  bias = g1b;    mm = mom; }
  else if (mode == 1) { x = guidance; w = fw;   bias = fb;     mm = mom + BB * CC; }
  else if (mode == 2) { x = guidance; w = hwt;  bias = hb;     mm = nullptr; }
  else                { x = G1in;     w = outw; bias = nullptr; mm = nullptr; }
  const float* xb = x + (size_t)b * CC * HWN;
  const float2* mb = mm ? mm + b * CC : nullptr;
  float acc[32];
#pragma unroll
  for (int gi = 0; gi < 32; ++gi) acc[gi] = bias ? bias[wid + 4 * gi] : 0.f;
  for (int c0 = 0; c0 < CC; c0 += 4) {
    float xv[4];
#pragma unroll
    for (int j = 0; j < 4; ++j) {
      float raw = xb[(size_t)(c0 + j) * HWN + p];
      if (mb) { float2 ms = mb[c0 + j]; raw = (raw - ms.x) * ms.y; }
      xv[j] = raw;
    }
#pragma unroll
    for (int gi = 0; gi < 32; ++gi) {
      const float4 wv = *(const float4*)(w + (wid + 4 * gi) * CC + c0);
      acc[gi] = fmaf(wv.x, xv[0], fmaf(wv.y, xv[1], fmaf(wv.z, xv[2], fmaf(wv.w, xv[3], acc[gi]))));
    }
  }
#pragma unroll
  for (int gi = 0; gi < 32; ++gi) {
    int o = wid + 4 * gi;
    float v = acc[gi];
    size_t idx = ((size_t)b * CC + o) * HWN + p;
    if (mode == 0) {
      G1[idx] = v;
      KTb[((size_t)b * HWN + p) * CC + o] = (__bf16)v;
    } else if (mode == 1) Qb[idx] = (__bf16)v;
    else if (mode == 2)   Vb[idx] = (__bf16)v;
    else                  Tf[idx] = v;
  }
}

// ---------------- flash attention: G2_pre[c,n] = sum_m V[c,m]*softmax_m(S[n,m]) --
// S[n,m] = sum_c Q[c,n]*K[c,m]. Swapped operands: MFMA1 computes S^T tiles so the
// P fragment is lane-local as MFMA2's B operand. 64 n per block, 16 n per wave.
__global__ __launch_bounds__(256, 1) void attn_kernel(
    const __bf16* __restrict__ Qb, const __bf16* __restrict__ KTb,
    const __bf16* __restrict__ Vb, float* __restrict__ G2p) {
  __shared__ __align__(16) char lds[65536];  // KT dbuf 2x16K @0, V dbuf 2x16K @32K
  int fid = blockIdx.x;
  int swz = (fid & 7) * 32 + (fid >> 3);  // chunked XCD swizzle (256 = 8*32)
  int b = swz >> 6;
  int ntile = swz & 63;
  int tid = threadIdx.x;
  int lane = tid & 63;
  int wid = tid >> 6;
  int l15 = lane & 15;
  int g = lane >> 4;  // 0..3
  int n_l = ntile * 64 + wid * 16 + l15;

  // Q fragments (B operand), stay in registers for all 64 KV tiles
  const __bf16* qbase = Qb + (size_t)b * CC * HWN + n_l;
  BF8 qf[4];
#pragma unroll
  for (int ch = 0; ch < 4; ++ch) {
#pragma unroll
    for (int j = 0; j < 8; ++j) {
      int c = ch * 32 + 4 * g + (j & 3) + 16 * (j >> 2);
      qf[ch].v[j] = qbase[(size_t)c * HWN];
    }
  }

  f32x4 Of[8];
#pragma unroll
  for (int cs = 0; cs < 8; ++cs) Of[cs] = (f32x4){0.f, 0.f, 0.f, 0.f};
  float mrun = -1e30f, lrun = 0.f;

  const char* ktB = (const char*)(KTb + (size_t)b * HWN * CC);  // [m][c] rows 256B
  const char* vB  = (const char*)(Vb + (size_t)b * CC * HWN);   // [c][m] rows

  auto stage = [&](int t, int bufsel) {
    int m0 = t * 64;
    char* kbase = lds + bufsel * 16384 + wid * 4096;
    char* vbase = lds + 32768 + bufsel * 16384 + wid * 4096;
#pragma unroll
    for (int i = 0; i < 4; ++i) {  // KT tile [64][256B], swizzle chunk^=(row&15)
      int row = wid * 16 + i * 4 + (lane >> 4);
      int chk = (lane & 15) ^ (row & 15);
      g2l16(kbase + i * 1024, ktB + (size_t)(m0 + row) * 256 + chk * 16);
    }
#pragma unroll
    for (int i = 0; i < 4; ++i) {  // V tile [128][128B], swizzle chunk^=(c&7)
      int c = wid * 32 + i * 8 + (lane >> 3);
      int chk = (lane & 7) ^ (c & 7);
      g2l16(vbase + i * 1024, vB + (size_t)c * (HWN * 2) + (size_t)m0 * 2 + chk * 16);
    }
  };

  auto compute = [&](int bufsel) {
    const char* kt = lds + bufsel * 16384;
    const char* vv = lds + 32768 + bufsel * 16384;
    f32x4 sacc[4];
#pragma unroll
    for (int ms = 0; ms < 4; ++ms) sacc[ms] = (f32x4){0.f, 0.f, 0.f, 0.f};
#pragma unroll
    for (int ch = 0; ch < 4; ++ch) {
      int cb2 = ch * 64 + 8 * g;  // byte offset of c-base within row
#pragma unroll
      for (int ms = 0; ms < 4; ++ms) {
        int row = ms * 16 + l15;
        int sw = (row & 15) << 4;
        BF8 af;
        af.h[0] = *(const bf16x4*)(kt + row * 256 + (cb2 ^ sw));
        af.h[1] = *(const bf16x4*)(kt + row * 256 + ((cb2 + 32) ^ sw));
        sacc[ms] = __builtin_amdgcn_mfma_f32_16x16x32_bf16(af.v, qf[ch].v, sacc[ms], 0, 0, 0);
      }
    }
    // online softmax per column n (lane&15); m spread over 4 lane-groups x 16 regs
    float tm = -1e30f;
#pragma unroll
    for (int ms = 0; ms < 4; ++ms)
#pragma unroll
      for (int r = 0; r < 4; ++r) tm = fmaxf(tm, sacc[ms][r]);
    tm = fmaxf(tm, __shfl_xor(tm, 16));
    tm = fmaxf(tm, __shfl_xor(tm, 32));
    float mnew = fmaxf(mrun, tm);
    float alpha = __expf(mrun - mnew);
    float ps = 0.f;
#pragma unroll
    for (int ms = 0; ms < 4; ++ms)
#pragma unroll
      for (int r = 0; r < 4; ++r) {
        float e = __expf(sacc[ms][r] - mnew);
        sacc[ms][r] = e;
        ps += e;
      }
    ps += __shfl_xor(ps, 16);
    ps += __shfl_xor(ps, 32);
    lrun = lrun * alpha + ps;
    mrun = mnew;
#pragma unroll
    for (int cs = 0; cs < 8; ++cs) Of[cs] *= alpha;
    BF8 pf[2];  // P^T as MFMA2 B operand: lane-local repack, no cross-lane moves
#pragma unroll
    for (int kc = 0; kc < 2; ++kc)
#pragma unroll
      for (int j = 0; j < 8; ++j)
        pf[kc].v[j] = (__bf16)sacc[2 * kc + (j >> 2)][j & 3];
#pragma unroll
    for (int cs = 0; cs < 8; ++cs) {
      int crow = cs * 16 + l15;
      int swv = (crow & 7) << 4;
#pragma unroll
      for (int kc = 0; kc < 2; ++kc) {
        int mb2 = kc * 64 + 8 * g;
        BF8 vf;
        vf.h[0] = *(const bf16x4*)(vv + crow * 128 + (mb2 ^ swv));
        vf.h[1] = *(const bf16x4*)(vv + crow * 128 + ((mb2 + 32) ^ swv));
        Of[cs] = __builtin_amdgcn_mfma_f32_16x16x32_bf16(vf.v, pf[kc].v, Of[cs], 0, 0, 0);
      }
    }
  };

  stage(0, 0);
  asm volatile("s_waitcnt vmcnt(0)" ::: "memory");
  __syncthreads();
  for (int t = 0; t < 64; ++t) {
    int bufsel = t & 1;
    if (t < 63) stage(t + 1, bufsel ^ 1);  // prefetch overlaps compute
    compute(bufsel);
    asm volatile("s_waitcnt vmcnt(0)" ::: "memory");
    __syncthreads();
  }

  float inv = 1.f / lrun;
  float* outp = G2p + (size_t)b * CC * HWN;
#pragma unroll
  for (int cs = 0; cs < 8; ++cs)
#pragma unroll
    for (int r = 0; r < 4; ++r)
      outp[(size_t)(cs * 16 + 4 * g + r) * HWN + n_l] = Of[cs][r] * inv;
}

// ---------------- per-(b,c) row softmax stats of G2_pre over n ------------------
__global__ __launch_bounds__(256) void smstats_kernel(
    const float* __restrict__ G2p, float2* __restrict__ smst) {
  int row = blockIdx.x;
  const float* x = G2p + (size_t)row * HWN;
  int tid = threadIdx.x;
  float v[16];
  float mx = -1e30f;
#pragma unroll
  for (int i = 0; i < 16; ++i) { v[i] = x[tid + i * 256]; mx = fmaxf(mx, v[i]); }
#pragma unroll
  for (int off = 32; off > 0; off >>= 1) mx = fmaxf(mx, __shfl_xor(mx, off));
  __shared__ float rm[4], rs[4];
  int wid = tid >> 6;
  if ((tid & 63) == 0) rm[wid] = mx;
  __syncthreads();
  float bmax = fmaxf(fmaxf(rm[0], rm[1]), fmaxf(rm[2], rm[3]));
  float s = 0.f;
#pragma unroll
  for (int i = 0; i < 16; ++i) s += __expf(v[i] - bmax);
#pragma unroll
  for (int off = 32; off > 0; off >>= 1) s += __shfl_xor(s, off);
  if ((tid & 63) == 0) rs[wid] = s;
  __syncthreads();
  if (tid == 0) {
    float tot = rs[0] + rs[1] + rs[2] + rs[3];
    smst[row] = make_float2(bmax, 1.f / tot);
  }
}

// ---------------- gamma/beta = channel-weighted sums of softmaxed G2 ------------
__global__ __launch_bounds__(256) void gammabeta_kernel(
    const float* __restrict__ G2p, const float2* __restrict__ smst,
    const float* __restrict__ gw, const float* __restrict__ bw,
    float* __restrict__ gamma, float* __restrict__ beta) {
  int b = blockIdx.y;
  int m = blockIdx.x * 256 + threadIdx.x;
  const float* base = G2p + (size_t)b * CC * HWN + m;
  float ag = 0.f, ab = 0.f;
  for (int c = 0; c < CC; ++c) {
    float2 st = smst[b * CC + c];
    float val = __expf(base[(size_t)c * HWN] - st.x) * st.y;
    ag = fmaf(gw[c], val, ag);
    ab = fmaf(bw[c], val, ab);
  }
  gamma[b * HWN + m] = ag;
  beta[b * HWN + m] = ab;
}

// ---- out[b,o] = T[b,o]@Gam[b] + rowsum(out_w[o,:])*Beta[b] + out_b[o] ----------
__global__ __launch_bounds__(256) void final_kernel(
    const float* __restrict__ Tf, const float* __restrict__ gamma,
    const float* __restrict__ beta, const float* __restrict__ outw,
    const float* __restrict__ outb, float* __restrict__ out) {
  int o = blockIdx.x, b = blockIdx.y;
  __shared__ float Ts[HWN], Gs[HWN];
  int tid = threadIdx.x;
  const float* tsrc = Tf + ((size_t)b * CC + o) * HWN;
  const float* gsrc = gamma + (size_t)b * HWN;
#pragma unroll
  for (int i = 0; i < 16; ++i) {
    Ts[tid + i * 256] = tsrc[tid + i * 256];
    Gs[tid + i * 256] = gsrc[tid + i * 256];
  }
  float wb = 0.f;
  for (int c = 0; c < CC; ++c) wb += outw[o * CC + c];
  float ob = outb[o];
  __syncthreads();
  int j = tid & 63, wid = tid >> 6;
  float* obase = out + ((size_t)b * CC + o) * HWN;
  const float* bbase = beta + (size_t)b * HWN;
  for (int r = 0; r < 16; ++r) {
    int i = r * 4 + wid;
    float a = 0.f;
    for (int k = 0; k < 64; ++k) a = fmaf(Ts[i * 64 + k], Gs[k * 64 + j], a);
    obase[i * 64 + j] = a + wb * bbase[i * 64 + j] + ob;
  }
}

extern "C" void kernel_launch(void* const* d_in, const int* in_sizes, int n_in,
                              void* d_out, int out_size, void* d_ws, size_t ws_size,
                              hipStream_t stream) {
  (void)in_sizes; (void)n_in; (void)out_size; (void)ws_size;
  const float* content  = (const float*)d_in[0];
  const float* guidance = (const float*)d_in[1];
  const float* g1w = (const float*)d_in[2];
  const float* g1b = (const float*)d_in[3];
  const float* fw  = (const float*)d_in[4];
  const float* fb  = (const float*)d_in[5];
  const float* hwt = (const float*)d_in[6];
  const float* hb  = (const float*)d_in[7];
  const float* gw  = (const float*)d_in[8];
  const float* bw  = (const float*)d_in[9];
  const float* outw = (const float*)d_in[10];
  const float* outb = (const float*)d_in[11];

  char* ws = (char*)d_ws;
  const size_t MB_ = 1u << 20;
  float*  G1  = (float*)(ws + 0);            // 8 MB
  float*  G2p = (float*)(ws + 8 * MB_);      // 8 MB
  __bf16* Qb  = (__bf16*)(ws + 16 * MB_);    // 4 MB
  __bf16* KTb = (__bf16*)(ws + 20 * MB_);    // 4 MB
  __bf16* Vb  = (__bf16*)(ws + 24 * MB_);    // 4 MB
  float*  Tf  = (float*)(ws + 16 * MB_);     // 8 MB, aliases Qb/KTb (dead after attn)
  float2* mom  = (float2*)(ws + 28 * MB_);            // 8 KB
  float2* smst = (float2*)(ws + 28 * MB_ + 8192);     // 4 KB
  float*  gamma = (float*)(ws + 28 * MB_ + 16384);    // 64 KB
  float*  beta  = (float*)(ws + 28 * MB_ + 16384 + 65536);  // 64 KB

  moments_kernel<<<dim3(BB * CC, 2), 256, 0, stream>>>(content, guidance, mom);
  conv_kernel<<<dim3(HWN / 64, BB, 3), 256, 0, stream>>>(
      content, guidance, G1, g1w, g1b, fw, fb, hwt, hb, outw, mom,
      G1, Tf, Qb, KTb, Vb, 0);
  attn_kernel<<<dim3(256), 256, 0, stream>>>(Qb, KTb, Vb, G2p);
  smstats_kernel<<<dim3(BB * CC), 256, 0, stream>>>(G2p, smst);
  gammabeta_kernel<<<dim3(HWN / 256, BB), 256, 0, stream>>>(G2p, smst, gw, bw, gamma, beta);
  conv_kernel<<<dim3(HWN / 64, BB, 1), 256, 0, stream>>>(
      content, guidance, G1, g1w, g1b, fw, fb, hwt, hb, outw, mom,
      G1, Tf, Qb, KTb, Vb, 3);
  final_kernel<<<dim3(CC, BB), 256, 0, stream>>>(Tf, gamma, beta, outw, outb, (float*)d_out);
}

// Round 2
// 251.969 us; speedup vs baseline: 1.1628x; 1.1628x over previous
//
#include <hip/hip_runtime.h>
#include <stdint.h>
#include <stddef.h>

#define BB 4
#define CC 128
#define HWN 4096

typedef __bf16 bf16x8 __attribute__((ext_vector_type(8)));
typedef float f32x4 __attribute__((ext_vector_type(4)));

__device__ __forceinline__ void g2l16(void* lds_ptr, const void* gptr) {
  __builtin_amdgcn_global_load_lds(
      (const __attribute__((address_space(1))) uint32_t*)gptr,
      (__attribute__((address_space(3))) uint32_t*)lds_ptr,
      16, 0, 0);
}

// fragment permutation within 32-element groups: x = 16h+4g+j -> 8g+4h+j
// makes each MFMA lane fragment (8 elems) contiguous 16B for ds_read_b128
__device__ __forceinline__ int perm32(int x) {
  return ((x & 12) << 1) | ((x & 16) >> 2) | (x & 3);
}

// ---------------- per-(b,c) mean/rstd over HW (unbiased var, +eps) -------------
__global__ __launch_bounds__(256) void moments_kernel(
    const float* __restrict__ content, const float* __restrict__ guidance,
    float2* __restrict__ mom) {
  int row = blockIdx.x;  // b*C + c
  const float* x = (blockIdx.y ? guidance : content) + (size_t)row * HWN;
  int tid = threadIdx.x;
  float s1 = 0.f, s2 = 0.f;
#pragma unroll
  for (int i = 0; i < 16; ++i) {
    float v = x[tid + i * 256];
    s1 += v; s2 += v * v;
  }
#pragma unroll
  for (int off = 32; off > 0; off >>= 1) {
    s1 += __shfl_down(s1, off);
    s2 += __shfl_down(s2, off);
  }
  __shared__ float r1[4], r2[4];
  int wid = tid >> 6;
  if ((tid & 63) == 0) { r1[wid] = s1; r2[wid] = s2; }
  __syncthreads();
  if (tid == 0) {
    float t1 = r1[0] + r1[1] + r1[2] + r1[3];
    float t2 = r2[0] + r2[1] + r2[2] + r2[3];
    float mean = t1 * (1.f / HWN);
    float var = (t2 - (float)HWN * mean * mean) * (1.f / (HWN - 1));
    mom[blockIdx.y * (BB * CC) + row] = make_float2(mean, rsqrtf(var + 1e-5f));
  }
}

// ---------------- 1x1 conv (optionally mvn-normalized input), f32 ---------------
// mode 0: G1 = g1w@mvn(content)+b  -> G1 f32 [b][c][p] + KT bf16 [b][p][permc]
// mode 1: Fm = fw@mvn(guidance)+b  -> QT bf16 [b][p][permc]
// mode 2: Hm = hw@guidance+b       -> V  bf16 [b][c][perm(p)]
// mode 3: T  = outw@G1             -> Tf f32  [b][c][p]
__global__ __launch_bounds__(256) void conv_kernel(
    const float* __restrict__ content, const float* __restrict__ guidance,
    const float* __restrict__ G1in,
    const float* __restrict__ g1w, const float* __restrict__ g1b,
    const float* __restrict__ fw, const float* __restrict__ fb,
    const float* __restrict__ hwt, const float* __restrict__ hb,
    const float* __restrict__ outw,
    const float2* __restrict__ mom,
    float* __restrict__ G1, float* __restrict__ Tf,
    __bf16* __restrict__ QTb, __bf16* __restrict__ KTb, __bf16* __restrict__ Vb,
    int zbase) {
  int mode = blockIdx.z + zbase;
  int b = blockIdx.y;
  int p = blockIdx.x * 64 + (threadIdx.x & 63);
  int wid = threadIdx.x >> 6;
  const float* x; const float* w; const float* bias; const float2* mm;
  if (mode == 0)      { x = content;  w = g1w;  bias = g1b;    mm = mom; }
  else if (mode == 1) { x = guidance; w = fw;   bias = fb;     mm = mom + BB * CC; }
  else if (mode == 2) { x = guidance; w = hwt;  bias = hb;     mm = nullptr; }
  else                { x = G1in;     w = outw; bias = nullptr; mm = nullptr; }
  const float* xb = x + (size_t)b * CC * HWN;
  const float2* mb = mm ? mm + b * CC : nullptr;
  float acc[32];
#pragma unroll
  for (int gi = 0; gi < 32; ++gi) acc[gi] = bias ? bias[wid + 4 * gi] : 0.f;
  for (int c0 = 0; c0 < CC; c0 += 4) {
    float xv[4];
#pragma unroll
    for (int j = 0; j < 4; ++j) {
      float raw = xb[(size_t)(c0 + j) * HWN + p];
      if (mb) { float2 ms = mb[c0 + j]; raw = (raw - ms.x) * ms.y; }
      xv[j] = raw;
    }
#pragma unroll
    for (int gi = 0; gi < 32; ++gi) {
      const float4 wv = *(const float4*)(w + (wid + 4 * gi) * CC + c0);
      acc[gi] = fmaf(wv.x, xv[0], fmaf(wv.y, xv[1], fmaf(wv.z, xv[2], fmaf(wv.w, xv[3], acc[gi]))));
    }
  }
  int pstore = (p & ~31) | perm32(p & 31);
#pragma unroll
  for (int gi = 0; gi < 32; ++gi) {
    int o = wid + 4 * gi;
    int ostore = (o & ~31) | perm32(o & 31);
    float v = acc[gi];
    if (mode == 0) {
      G1[((size_t)b * CC + o) * HWN + p] = v;
      KTb[((size_t)b * HWN + p) * CC + ostore] = (__bf16)v;
    } else if (mode == 1) {
      QTb[((size_t)b * HWN + p) * CC + ostore] = (__bf16)v;
    } else if (mode == 2) {
      Vb[((size_t)b * CC + o) * HWN + pstore] = (__bf16)v;
    } else {
      Tf[((size_t)b * CC + o) * HWN + p] = v;
    }
  }
}

// ---------------- flash attention: G2_pre[c,n] = sum_m V[c,m]*softmax_m(S[n,m]) --
// 8 waves: group 0 (waves 0-3) even KV tiles, group 1 odd; merge at end.
// All operands fragment-permuted so every MFMA A-frag is one ds_read_b128,
// XOR-swizzled (chunk ^= row&7) => conflict-free.
__global__ __launch_bounds__(512, 1) void attn_kernel(
    const __bf16* __restrict__ QTb, const __bf16* __restrict__ KTb,
    const __bf16* __restrict__ Vb, float* __restrict__ G2p) {
  __shared__ __align__(16) char lds[131072];  // 4 bufs x (K 16K + V 16K)
  int fid = blockIdx.x;
  int swz = (fid & 7) * 32 + (fid >> 3);  // XCD swizzle: 32 consecutive tiles/XCD
  int b = swz >> 6;
  int ntile = swz & 63;
  int tid = threadIdx.x;
  int lane = tid & 63;
  int wid = tid >> 6;   // 0..7
  int grp = wid >> 2;   // 0: even tiles, 1: odd tiles
  int w4 = wid & 3;
  int l15 = lane & 15;
  int g = lane >> 4;
  int n_l = ntile * 64 + w4 * 16 + l15;

  // Q fragments: contiguous 16B in permuted QT layout
  const __bf16* qrow = QTb + ((size_t)b * HWN + n_l) * CC;
  bf16x8 qf[4];
#pragma unroll
  for (int ch = 0; ch < 4; ++ch)
    qf[ch] = *(const bf16x8*)(qrow + ch * 32 + g * 8);

  f32x4 Of[8];
#pragma unroll
  for (int cs = 0; cs < 8; ++cs) Of[cs] = (f32x4){0.f, 0.f, 0.f, 0.f};
  float mrun = -1e30f, lrun = 0.f;

  const char* ktB = (const char*)(KTb + (size_t)b * HWN * CC);  // [m][permc], 256B rows
  const char* vB  = (const char*)(Vb + (size_t)b * CC * HWN);   // [c][perm m], 8192B rows

  // stage tile t (64 m) into buf: K by waves 0-3, V by waves 4-7.
  // LDS dest linear, global source inverse-swizzled (chunk ^ row&7).
  auto stage = [&](int t, char* buf) {
    int m0 = t * 64;
    if (wid < 4) {
      char* kb = buf + wid * 4096;
#pragma unroll
      for (int i = 0; i < 4; ++i) {
        int row = wid * 16 + i * 4 + (lane >> 4);
        int chk = (lane & 15) ^ (row & 7);
        g2l16(kb + i * 1024, ktB + (size_t)(m0 + row) * 256 + chk * 16);
      }
    } else {
      char* vb = buf + 16384 + (wid - 4) * 4096;
#pragma unroll
      for (int i = 0; i < 4; ++i) {
        int c = (wid - 4) * 32 + i * 8 + (lane >> 3);
        int chk = (lane & 7) ^ (c & 7);
        g2l16(vb + i * 1024, vB + (size_t)c * (HWN * 2) + (size_t)m0 * 2 + chk * 16);
      }
    }
  };

  auto compute = [&](const char* buf) {
    const char* kt = buf;
    const char* vv = buf + 16384;
    f32x4 sacc[4];
#pragma unroll
    for (int ms = 0; ms < 4; ++ms) sacc[ms] = (f32x4){0.f, 0.f, 0.f, 0.f};
#pragma unroll
    for (int ch = 0; ch < 4; ++ch) {
#pragma unroll
      for (int ms = 0; ms < 4; ++ms) {
        int row = ms * 16 + l15;
        bf16x8 af = *(const bf16x8*)(kt + row * 256 + (((ch * 4 + g) ^ (row & 7)) << 4));
        sacc[ms] = __builtin_amdgcn_mfma_f32_16x16x32_bf16(af, qf[ch], sacc[ms], 0, 0, 0);
      }
    }
    float tm = -1e30f;
#pragma unroll
    for (int ms = 0; ms < 4; ++ms)
#pragma unroll
      for (int r = 0; r < 4; ++r) tm = fmaxf(tm, sacc[ms][r]);
    tm = fmaxf(tm, __shfl_xor(tm, 16));
    tm = fmaxf(tm, __shfl_xor(tm, 32));
    if (!__all(tm <= mrun + 8.f)) {  // defer-max: rescale only on real growth
      float mnew = fmaxf(mrun, tm);
      float alpha = __expf(mrun - mnew);
      lrun *= alpha;
#pragma unroll
      for (int cs = 0; cs < 8; ++cs) Of[cs] *= alpha;
      mrun = mnew;
    }
    float ps = 0.f;
#pragma unroll
    for (int ms = 0; ms < 4; ++ms)
#pragma unroll
      for (int r = 0; r < 4; ++r) {
        float e = __expf(sacc[ms][r] - mrun);
        sacc[ms][r] = e;
        ps += e;
      }
    ps += __shfl_xor(ps, 16);
    ps += __shfl_xor(ps, 32);
    lrun += ps;
    bf16x8 pf[2];  // P^T fragment: lane-local repack
#pragma unroll
    for (int kc = 0; kc < 2; ++kc)
#pragma unroll
      for (int j = 0; j < 8; ++j)
        pf[kc][j] = (__bf16)sacc[2 * kc + (j >> 2)][j & 3];
#pragma unroll
    for (int cs = 0; cs < 8; ++cs) {
      int crow = cs * 16 + l15;
#pragma unroll
      for (int kc = 0; kc < 2; ++kc) {
        bf16x8 vf = *(const bf16x8*)(vv + crow * 128 + (((kc * 4 + g) ^ (crow & 7)) << 4));
        Of[cs] = __builtin_amdgcn_mfma_f32_16x16x32_bf16(vf, pf[kc], Of[cs], 0, 0, 0);
      }
    }
  };

  stage(0, lds);
  stage(1, lds + 32768);
  asm volatile("s_waitcnt vmcnt(0)" ::: "memory");
  __syncthreads();
  for (int pt = 0; pt < 32; ++pt) {
    int cur = (pt & 1) * 2;
    if (pt < 31) {  // prefetch next pair into the other two bufs
      stage(2 * pt + 2, lds + (size_t)(cur ^ 2) * 32768);
      stage(2 * pt + 3, lds + (size_t)((cur ^ 2) + 1) * 32768);
    }
    compute(lds + (size_t)(cur + grp) * 32768);
    asm volatile("s_waitcnt vmcnt(0)" ::: "memory");
    __syncthreads();
  }

  // merge the two m-split partials (group 1 -> LDS, group 0 combines)
  float* xch = (float*)lds;
  int slot = (w4 * 64 + lane) * 36;  // 144B stride: conflict-free
  if (grp == 1) {
#pragma unroll
    for (int cs = 0; cs < 8; ++cs)
      *(f32x4*)(xch + slot + cs * 4) = Of[cs];
    xch[slot + 32] = mrun;
    xch[slot + 33] = lrun;
  }
  __syncthreads();
  if (grp == 0) {
    float m1 = xch[slot + 32], l1 = xch[slot + 33];
    float msf = fmaxf(mrun, m1);
    float a0 = __expf(mrun - msf), a1 = __expf(m1 - msf);
    float inv = 1.f / (lrun * a0 + l1 * a1);
    float* outp = G2p + (size_t)b * CC * HWN;
#pragma unroll
    for (int cs = 0; cs < 8; ++cs) {
      f32x4 o1 = *(const f32x4*)(xch + slot + cs * 4);
#pragma unroll
      for (int r = 0; r < 4; ++r)
        outp[(size_t)(cs * 16 + 4 * g + r) * HWN + n_l] = (Of[cs][r] * a0 + o1[r] * a1) * inv;
    }
  }
}

// ---------------- per-(b,c) row softmax stats of G2_pre over n ------------------
__global__ __launch_bounds__(256) void smstats_kernel(
    const float* __restrict__ G2p, float2* __restrict__ smst) {
  int row = blockIdx.x;
  const float* x = G2p + (size_t)row * HWN;
  int tid = threadIdx.x;
  float v[16];
  float mx = -1e30f;
#pragma unroll
  for (int i = 0; i < 16; ++i) { v[i] = x[tid + i * 256]; mx = fmaxf(mx, v[i]); }
#pragma unroll
  for (int off = 32; off > 0; off >>= 1) mx = fmaxf(mx, __shfl_xor(mx, off));
  __shared__ float rm[4], rs[4];
  int wid = tid >> 6;
  if ((tid & 63) == 0) rm[wid] = mx;
  __syncthreads();
  float bmax = fmaxf(fmaxf(rm[0], rm[1]), fmaxf(rm[2], rm[3]));
  float s = 0.f;
#pragma unroll
  for (int i = 0; i < 16; ++i) s += __expf(v[i] - bmax);
#pragma unroll
  for (int off = 32; off > 0; off >>= 1) s += __shfl_xor(s, off);
  if ((tid & 63) == 0) rs[wid] = s;
  __syncthreads();
  if (tid == 0) {
    float tot = rs[0] + rs[1] + rs[2] + rs[3];
    smst[row] = make_float2(bmax, 1.f / tot);
  }
}

// ---------------- gamma/beta = channel-weighted sums of softmaxed G2 ------------
__global__ __launch_bounds__(256) void gammabeta_kernel(
    const float* __restrict__ G2p, const float2* __restrict__ smst,
    const float* __restrict__ gw, const float* __restrict__ bw,
    float* __restrict__ gamma, float* __restrict__ beta) {
  int b = blockIdx.y;
  int m = blockIdx.x * 256 + threadIdx.x;
  const float* base = G2p + (size_t)b * CC * HWN + m;
  float ag = 0.f, ab = 0.f;
  for (int c = 0; c < CC; ++c) {
    float2 st = smst[b * CC + c];
    float val = __expf(base[(size_t)c * HWN] - st.x) * st.y;
    ag = fmaf(gw[c], val, ag);
    ab = fmaf(bw[c], val, ab);
  }
  gamma[b * HWN + m] = ag;
  beta[b * HWN + m] = ab;
}

// ---- out[b,o] = T[b,o]@Gam[b] + rowsum(out_w[o,:])*Beta[b] + out_b[o] ----------
__global__ __launch_bounds__(256) void final_kernel(
    const float* __restrict__ Tf, const float* __restrict__ gamma,
    const float* __restrict__ beta, const float* __restrict__ outw,
    const float* __restrict__ outb, float* __restrict__ out) {
  int o = blockIdx.x, b = blockIdx.y;
  __shared__ float Ts[HWN], Gs[HWN];
  int tid = threadIdx.x;
  const float* tsrc = Tf + ((size_t)b * CC + o) * HWN;
  const float* gsrc = gamma + (size_t)b * HWN;
#pragma unroll
  for (int i = 0; i < 16; ++i) {
    Ts[tid + i * 256] = tsrc[tid + i * 256];
    Gs[tid + i * 256] = gsrc[tid + i * 256];
  }
  float wb = 0.f;
  for (int c = 0; c < CC; ++c) wb += outw[o * CC + c];
  float ob = outb[o];
  __syncthreads();
  int j = tid & 63, wid = tid >> 6;
  float* obase = out + ((size_t)b * CC + o) * HWN;
  const float* bbase = beta + (size_t)b * HWN;
  for (int r = 0; r < 16; ++r) {
    int i = r * 4 + wid;
    float a = 0.f;
    for (int k = 0; k < 64; ++k) a = fmaf(Ts[i * 64 + k], Gs[k * 64 + j], a);
    obase[i * 64 + j] = a + wb * bbase[i * 64 + j] + ob;
  }
}

extern "C" void kernel_launch(void* const* d_in, const int* in_sizes, int n_in,
                              void* d_out, int out_size, void* d_ws, size_t ws_size,
                              hipStream_t stream) {
  (void)in_sizes; (void)n_in; (void)out_size; (void)ws_size;
  const float* content  = (const float*)d_in[0];
  const float* guidance = (const float*)d_in[1];
  const float* g1w = (const float*)d_in[2];
  const float* g1b = (const float*)d_in[3];
  const float* fw  = (const float*)d_in[4];
  const float* fb  = (const float*)d_in[5];
  const float* hwt = (const float*)d_in[6];
  const float* hb  = (const float*)d_in[7];
  const float* gw  = (const float*)d_in[8];
  const float* bw  = (const float*)d_in[9];
  const float* outw = (const float*)d_in[10];
  const float* outb = (const float*)d_in[11];

  char* ws = (char*)d_ws;
  const size_t MB_ = 1u << 20;
  float*  G1  = (float*)(ws + 0);            // 8 MB
  float*  G2p = (float*)(ws + 8 * MB_);      // 8 MB
  __bf16* QTb = (__bf16*)(ws + 16 * MB_);    // 4 MB
  __bf16* KTb = (__bf16*)(ws + 20 * MB_);    // 4 MB
  __bf16* Vb  = (__bf16*)(ws + 24 * MB_);    // 4 MB
  float*  Tf  = (float*)(ws + 16 * MB_);     // 8 MB, aliases QT/KT (dead after attn)
  float2* mom  = (float2*)(ws + 28 * MB_);            // 8 KB
  float2* smst = (float2*)(ws + 28 * MB_ + 8192);     // 4 KB
  float*  gamma = (float*)(ws + 28 * MB_ + 16384);    // 64 KB
  float*  beta  = (float*)(ws + 28 * MB_ + 16384 + 65536);  // 64 KB

  moments_kernel<<<dim3(BB * CC, 2), 256, 0, stream>>>(content, guidance, mom);
  conv_kernel<<<dim3(HWN / 64, BB, 3), 256, 0, stream>>>(
      content, guidance, G1, g1w, g1b, fw, fb, hwt, hb, outw, mom,
      G1, Tf, QTb, KTb, Vb, 0);
  attn_kernel<<<dim3(256), 512, 0, stream>>>(QTb, KTb, Vb, G2p);
  smstats_kernel<<<dim3(BB * CC), 256, 0, stream>>>(G2p, smst);
  gammabeta_kernel<<<dim3(HWN / 256, BB), 256, 0, stream>>>(G2p, smst, gw, bw, gamma, beta);
  conv_kernel<<<dim3(HWN / 64, BB, 1), 256, 0, stream>>>(
      content, guidance, G1, g1w, g1b, fw, fb, hwt, hb, outw, mom,
      G1, Tf, QTb, KTb, Vb, 3);
  final_kernel<<<dim3(CC, BB), 256, 0, stream>>>(Tf, gamma, beta, outw, outb, (float*)d_out);
}

// Round 3
// 176.819 us; speedup vs baseline: 1.6570x; 1.4250x over previous
//
#include <hip/hip_runtime.h>
#include <stdint.h>
#include <stddef.h>

#define BB 4
#define CC 128
#define HWN 4096

typedef __bf16 bf16x2 __attribute__((ext_vector_type(2)));
typedef __bf16 bf16x8 __attribute__((ext_vector_type(8)));
typedef float f32x4 __attribute__((ext_vector_type(4)));

__device__ __forceinline__ void g2l16(void* lds_ptr, const void* gptr) {
  __builtin_amdgcn_global_load_lds(
      (const __attribute__((address_space(1))) uint32_t*)gptr,
      (__attribute__((address_space(3))) uint32_t*)lds_ptr,
      16, 0, 0);
}

// fragment permutation within 32-element groups: x = 16h+4g+j -> 8g+4h+j
__device__ __forceinline__ int perm32(int x) {
  return ((x & 12) << 1) | ((x & 16) >> 2) | (x & 3);
}

// ---------------- per-(b,c) mean/rstd over HW (unbiased var, +eps) -------------
__global__ __launch_bounds__(256) void moments_kernel(
    const float* __restrict__ content, const float* __restrict__ guidance,
    float2* __restrict__ mom) {
  int row = blockIdx.x;  // b*C + c
  const float* x = (blockIdx.y ? guidance : content) + (size_t)row * HWN;
  int tid = threadIdx.x;
  float s1 = 0.f, s2 = 0.f;
#pragma unroll
  for (int i = 0; i < 16; ++i) {
    float v = x[tid + i * 256];
    s1 += v; s2 += v * v;
  }
#pragma unroll
  for (int off = 32; off > 0; off >>= 1) {
    s1 += __shfl_down(s1, off);
    s2 += __shfl_down(s2, off);
  }
  __shared__ float r1[4], r2[4];
  int wid = tid >> 6;
  if ((tid & 63) == 0) { r1[wid] = s1; r2[wid] = s2; }
  __syncthreads();
  if (tid == 0) {
    float t1 = r1[0] + r1[1] + r1[2] + r1[3];
    float t2 = r2[0] + r2[1] + r2[2] + r2[3];
    float mean = t1 * (1.f / HWN);
    float var = (t2 - (float)HWN * mean * mean) * (1.f / (HWN - 1));
    mom[blockIdx.y * (BB * CC) + row] = make_float2(mean, rsqrtf(var + 1e-5f));
  }
}

// ---------------- 1x1 conv (optionally mvn-normalized input), f32 ---------------
// zc = blockIdx.z + zbase; mode = zc>>1; ohalf = zc&1 (64 outputs per block).
// mode 0: G1 = g1w@mvn(content)+b  -> G1 f32 [b][c][p] + KT bf16 [b][p][permc]
// mode 1: Fm = fw@mvn(guidance)+b  -> QT bf16 [b][p][permc]
// mode 2: Hm = hw@guidance+b       -> V  bf16 [b][c][perm(p)]
// mode 3: T  = outw@G1             -> Tf f32  [b][c][p]
// Weight rows are fetched via readfirstlane-scalar addresses -> s_load broadcast.
__global__ __launch_bounds__(256) void conv_kernel(
    const float* __restrict__ content, const float* __restrict__ guidance,
    const float* __restrict__ G1in,
    const float* __restrict__ g1w, const float* __restrict__ g1b,
    const float* __restrict__ fw, const float* __restrict__ fb,
    const float* __restrict__ hwt, const float* __restrict__ hb,
    const float* __restrict__ outw,
    const float2* __restrict__ mom,
    float* __restrict__ G1, float* __restrict__ Tf,
    __bf16* __restrict__ QTb, __bf16* __restrict__ KTb, __bf16* __restrict__ Vb,
    int zbase) {
  int zc = blockIdx.z + zbase;
  int mode = zc >> 1;
  int ohalf = zc & 1;
  int b = blockIdx.y;
  int lane = threadIdx.x & 63;
  int wid = threadIdx.x >> 6;
  int swid = __builtin_amdgcn_readfirstlane(wid);
  int p = blockIdx.x * 64 + lane;
  const float* x; const float* w; const float* bias; const float2* mm;
  if (mode == 0)      { x = content;  w = g1w;  bias = g1b;    mm = mom; }
  else if (mode == 1) { x = guidance; w = fw;   bias = fb;     mm = mom + BB * CC; }
  else if (mode == 2) { x = guidance; w = hwt;  bias = hb;     mm = nullptr; }
  else                { x = G1in;     w = outw; bias = nullptr; mm = nullptr; }
  const float* xb = x + (size_t)b * CC * HWN;
  const float2* mb = mm ? mm + b * CC : nullptr;
  // thread owns o = obase + 8*k + j, j in {0,1}, k in 0..7 (adjacent perm pairs)
  int obase = ohalf * 64 + 2 * wid;
  const float* wbase = w + (size_t)(ohalf * 64 + 2 * swid) * CC;  // scalar base
  float acc[16];
#pragma unroll
  for (int k = 0; k < 8; ++k) {
    acc[2 * k]     = bias ? bias[obase + 8 * k]     : 0.f;
    acc[2 * k + 1] = bias ? bias[obase + 8 * k + 1] : 0.f;
  }
  for (int c0 = 0; c0 < CC; c0 += 4) {
    float xv[4];
#pragma unroll
    for (int j = 0; j < 4; ++j) {
      float raw = xb[(size_t)(c0 + j) * HWN + p];
      if (mb) { float2 ms = mb[c0 + j]; raw = (raw - ms.x) * ms.y; }
      xv[j] = raw;
    }
#pragma unroll
    for (int k = 0; k < 8; ++k) {
      const float4 w0 = *(const float4*)(wbase + (size_t)(8 * k) * CC + c0);
      const float4 w1 = *(const float4*)(wbase + (size_t)(8 * k + 1) * CC + c0);
      acc[2 * k]     = fmaf(w0.x, xv[0], fmaf(w0.y, xv[1], fmaf(w0.z, xv[2], fmaf(w0.w, xv[3], acc[2 * k]))));
      acc[2 * k + 1] = fmaf(w1.x, xv[0], fmaf(w1.y, xv[1], fmaf(w1.z, xv[2], fmaf(w1.w, xv[3], acc[2 * k + 1]))));
    }
  }
  if (mode == 0 || mode == 1) {
    __bf16* T = (mode == 0) ? KTb : QTb;
    char* rowp = (char*)(T + ((size_t)b * HWN + p) * CC);
#pragma unroll
    for (int k = 0; k < 8; ++k) {
      int o0 = obase + 8 * k;
      int pp = (o0 & ~31) | perm32(o0 & 31);  // o0 even -> pp, pp+1 adjacent
      bf16x2 pr = {(__bf16)acc[2 * k], (__bf16)acc[2 * k + 1]};
      *(bf16x2*)(rowp + pp * 2) = pr;
    }
    if (mode == 0) {
#pragma unroll
      for (int k = 0; k < 8; ++k) {
        int o0 = obase + 8 * k;
        G1[((size_t)b * CC + o0) * HWN + p] = acc[2 * k];
        G1[((size_t)b * CC + o0 + 1) * HWN + p] = acc[2 * k + 1];
      }
    }
  } else if (mode == 2) {
    int pstore = (p & ~31) | perm32(p & 31);
#pragma unroll
    for (int k = 0; k < 8; ++k) {
      int o0 = obase + 8 * k;
      Vb[((size_t)b * CC + o0) * HWN + pstore] = (__bf16)acc[2 * k];
      Vb[((size_t)b * CC + o0 + 1) * HWN + pstore] = (__bf16)acc[2 * k + 1];
    }
  } else {
#pragma unroll
    for (int k = 0; k < 8; ++k) {
      int o0 = obase + 8 * k;
      Tf[((size_t)b * CC + o0) * HWN + p] = acc[2 * k];
      Tf[((size_t)b * CC + o0 + 1) * HWN + p] = acc[2 * k + 1];
    }
  }
}

// ---------------- flash attention: G2_pre[c,n] = sum_m V[c,m]*softmax_m(S[n,m]) --
__global__ __launch_bounds__(512, 1) void attn_kernel(
    const __bf16* __restrict__ QTb, const __bf16* __restrict__ KTb,
    const __bf16* __restrict__ Vb, float* __restrict__ G2p) {
  __shared__ __align__(16) char lds[131072];  // 4 bufs x (K 16K + V 16K)
  int fid = blockIdx.x;
  int swz = (fid & 7) * 32 + (fid >> 3);  // XCD swizzle
  int b = swz >> 6;
  int ntile = swz & 63;
  int tid = threadIdx.x;
  int lane = tid & 63;
  int wid = tid >> 6;   // 0..7
  int grp = wid >> 2;   // 0: even tiles, 1: odd tiles
  int w4 = wid & 3;
  int l15 = lane & 15;
  int g = lane >> 4;
  int n_l = ntile * 64 + w4 * 16 + l15;

  const __bf16* qrow = QTb + ((size_t)b * HWN + n_l) * CC;
  bf16x8 qf[4];
#pragma unroll
  for (int ch = 0; ch < 4; ++ch)
    qf[ch] = *(const bf16x8*)(qrow + ch * 32 + g * 8);

  f32x4 Of[8];
#pragma unroll
  for (int cs = 0; cs < 8; ++cs) Of[cs] = (f32x4){0.f, 0.f, 0.f, 0.f};
  float mrun = -1e30f, lrun = 0.f;

  const char* ktB = (const char*)(KTb + (size_t)b * HWN * CC);  // [m][permc]
  const char* vB  = (const char*)(Vb + (size_t)b * CC * HWN);   // [c][perm m]

  auto stage = [&](int t, char* buf) {
    int m0 = t * 64;
    if (wid < 4) {
      char* kb = buf + wid * 4096;
#pragma unroll
      for (int i = 0; i < 4; ++i) {
        int row = wid * 16 + i * 4 + (lane >> 4);
        int chk = (lane & 15) ^ (row & 7);
        g2l16(kb + i * 1024, ktB + (size_t)(m0 + row) * 256 + chk * 16);
      }
    } else {
      char* vb = buf + 16384 + (wid - 4) * 4096;
#pragma unroll
      for (int i = 0; i < 4; ++i) {
        int c = (wid - 4) * 32 + i * 8 + (lane >> 3);
        int chk = (lane & 7) ^ (c & 7);
        g2l16(vb + i * 1024, vB + (size_t)c * (HWN * 2) + (size_t)m0 * 2 + chk * 16);
      }
    }
  };

  auto compute = [&](const char* buf) {
    const char* kt = buf;
    const char* vv = buf + 16384;
    f32x4 sacc[4];
#pragma unroll
    for (int ms = 0; ms < 4; ++ms) sacc[ms] = (f32x4){0.f, 0.f, 0.f, 0.f};
#pragma unroll
    for (int ch = 0; ch < 4; ++ch) {
#pragma unroll
      for (int ms = 0; ms < 4; ++ms) {
        int row = ms * 16 + l15;
        bf16x8 af = *(const bf16x8*)(kt + row * 256 + (((ch * 4 + g) ^ (row & 7)) << 4));
        sacc[ms] = __builtin_amdgcn_mfma_f32_16x16x32_bf16(af, qf[ch], sacc[ms], 0, 0, 0);
      }
    }
    float tm = -1e30f;
#pragma unroll
    for (int ms = 0; ms < 4; ++ms)
#pragma unroll
      for (int r = 0; r < 4; ++r) tm = fmaxf(tm, sacc[ms][r]);
    tm = fmaxf(tm, __shfl_xor(tm, 16));
    tm = fmaxf(tm, __shfl_xor(tm, 32));
    if (!__all(tm <= mrun + 8.f)) {  // defer-max
      float mnew = fmaxf(mrun, tm);
      float alpha = __expf(mrun - mnew);
      lrun *= alpha;
#pragma unroll
      for (int cs = 0; cs < 8; ++cs) Of[cs] *= alpha;
      mrun = mnew;
    }
    float ps = 0.f;
#pragma unroll
    for (int ms = 0; ms < 4; ++ms)
#pragma unroll
      for (int r = 0; r < 4; ++r) {
        float e = __expf(sacc[ms][r] - mrun);
        sacc[ms][r] = e;
        ps += e;
      }
    ps += __shfl_xor(ps, 16);
    ps += __shfl_xor(ps, 32);
    lrun += ps;
    bf16x8 pf[2];
#pragma unroll
    for (int kc = 0; kc < 2; ++kc)
#pragma unroll
      for (int j = 0; j < 8; ++j)
        pf[kc][j] = (__bf16)sacc[2 * kc + (j >> 2)][j & 3];
#pragma unroll
    for (int cs = 0; cs < 8; ++cs) {
      int crow = cs * 16 + l15;
#pragma unroll
      for (int kc = 0; kc < 2; ++kc) {
        bf16x8 vf = *(const bf16x8*)(vv + crow * 128 + (((kc * 4 + g) ^ (crow & 7)) << 4));
        Of[cs] = __builtin_amdgcn_mfma_f32_16x16x32_bf16(vf, pf[kc], Of[cs], 0, 0, 0);
      }
    }
  };

  stage(0, lds);
  stage(1, lds + 32768);
  asm volatile("s_waitcnt vmcnt(0)" ::: "memory");
  __syncthreads();
  for (int pt = 0; pt < 32; ++pt) {
    int cur = (pt & 1) * 2;
    if (pt < 31) {
      stage(2 * pt + 2, lds + (size_t)(cur ^ 2) * 32768);
      stage(2 * pt + 3, lds + (size_t)((cur ^ 2) + 1) * 32768);
    }
    compute(lds + (size_t)(cur + grp) * 32768);
    asm volatile("s_waitcnt vmcnt(0)" ::: "memory");
    __syncthreads();
  }

  float* xch = (float*)lds;
  int slot = (w4 * 64 + lane) * 36;
  if (grp == 1) {
#pragma unroll
    for (int cs = 0; cs < 8; ++cs)
      *(f32x4*)(xch + slot + cs * 4) = Of[cs];
    xch[slot + 32] = mrun;
    xch[slot + 33] = lrun;
  }
  __syncthreads();
  if (grp == 0) {
    float m1 = xch[slot + 32], l1 = xch[slot + 33];
    float msf = fmaxf(mrun, m1);
    float a0 = __expf(mrun - msf), a1 = __expf(m1 - msf);
    float inv = 1.f / (lrun * a0 + l1 * a1);
    float* outp = G2p + (size_t)b * CC * HWN;
#pragma unroll
    for (int cs = 0; cs < 8; ++cs) {
      f32x4 o1 = *(const f32x4*)(xch + slot + cs * 4);
#pragma unroll
      for (int r = 0; r < 4; ++r)
        outp[(size_t)(cs * 16 + 4 * g + r) * HWN + n_l] = (Of[cs][r] * a0 + o1[r] * a1) * inv;
    }
  }
}

// ---------------- per-(b,c) row softmax stats of G2_pre over n ------------------
__global__ __launch_bounds__(256) void smstats_kernel(
    const float* __restrict__ G2p, float2* __restrict__ smst) {
  int row = blockIdx.x;
  const float* x = G2p + (size_t)row * HWN;
  int tid = threadIdx.x;
  float v[16];
  float mx = -1e30f;
#pragma unroll
  for (int i = 0; i < 16; ++i) { v[i] = x[tid + i * 256]; mx = fmaxf(mx, v[i]); }
#pragma unroll
  for (int off = 32; off > 0; off >>= 1) mx = fmaxf(mx, __shfl_xor(mx, off));
  __shared__ float rm[4], rs[4];
  int wid = tid >> 6;
  if ((tid & 63) == 0) rm[wid] = mx;
  __syncthreads();
  float bmax = fmaxf(fmaxf(rm[0], rm[1]), fmaxf(rm[2], rm[3]));
  float s = 0.f;
#pragma unroll
  for (int i = 0; i < 16; ++i) s += __expf(v[i] - bmax);
#pragma unroll
  for (int off = 32; off > 0; off >>= 1) s += __shfl_xor(s, off);
  if ((tid & 63) == 0) rs[wid] = s;
  __syncthreads();
  if (tid == 0) {
    float tot = rs[0] + rs[1] + rs[2] + rs[3];
    smst[row] = make_float2(bmax, 1.f / tot);
  }
}

// ---------------- gamma/beta = channel-weighted sums of softmaxed G2 ------------
// grid (HWN/64, BB); 4 c-groups of 32 per block, LDS-reduced.
__global__ __launch_bounds__(256) void gammabeta_kernel(
    const float* __restrict__ G2p, const float2* __restrict__ smst,
    const float* __restrict__ gw, const float* __restrict__ bw,
    float* __restrict__ gamma, float* __restrict__ beta) {
  int b = blockIdx.y;
  int lane = threadIdx.x & 63;
  int cg = threadIdx.x >> 6;
  int m = blockIdx.x * 64 + lane;
  const float* base = G2p + (size_t)b * CC * HWN + m;
  float ag = 0.f, ab = 0.f;
#pragma unroll 8
  for (int ci = 0; ci < 32; ++ci) {
    int c = cg * 32 + ci;
    float2 st = smst[b * CC + c];
    float val = __expf(base[(size_t)c * HWN] - st.x) * st.y;
    ag = fmaf(gw[c], val, ag);
    ab = fmaf(bw[c], val, ab);
  }
  __shared__ float sg[4][64], sb[4][64];
  sg[cg][lane] = ag;
  sb[cg][lane] = ab;
  __syncthreads();
  if (threadIdx.x < 64) {
    int t = threadIdx.x;
    gamma[b * HWN + blockIdx.x * 64 + t] = sg[0][t] + sg[1][t] + sg[2][t] + sg[3][t];
    beta[b * HWN + blockIdx.x * 64 + t]  = sb[0][t] + sb[1][t] + sb[2][t] + sb[3][t];
  }
}

// ---- out[b,o] = T[b,o]@Gam[b] + rowsum(out_w[o,:])*Beta[b] + out_b[o] ----------
__global__ __launch_bounds__(256) void final_kernel(
    const float* __restrict__ Tf, const float* __restrict__ gamma,
    const float* __restrict__ beta, const float* __restrict__ outw,
    const float* __restrict__ outb, float* __restrict__ out) {
  int o = blockIdx.x, b = blockIdx.y;
  __shared__ float Ts[HWN], Gs[HWN];
  int tid = threadIdx.x;
  const float* tsrc = Tf + ((size_t)b * CC + o) * HWN;
  const float* gsrc = gamma + (size_t)b * HWN;
#pragma unroll
  for (int i = 0; i < 16; ++i) {
    Ts[tid + i * 256] = tsrc[tid + i * 256];
    Gs[tid + i * 256] = gsrc[tid + i * 256];
  }
  float wb = 0.f;
  for (int c = 0; c < CC; ++c) wb += outw[o * CC + c];
  float ob = outb[o];
  __syncthreads();
  int j = tid & 63, wid = tid >> 6;
  float* obase = out + ((size_t)b * CC + o) * HWN;
  const float* bbase = beta + (size_t)b * HWN;
  for (int r = 0; r < 16; ++r) {
    int i = r * 4 + wid;
    float a = 0.f;
    for (int k = 0; k < 64; ++k) a = fmaf(Ts[i * 64 + k], Gs[k * 64 + j], a);
    obase[i * 64 + j] = a + wb * bbase[i * 64 + j] + ob;
  }
}

extern "C" void kernel_launch(void* const* d_in, const int* in_sizes, int n_in,
                              void* d_out, int out_size, void* d_ws, size_t ws_size,
                              hipStream_t stream) {
  (void)in_sizes; (void)n_in; (void)out_size; (void)ws_size;
  const float* content  = (const float*)d_in[0];
  const float* guidance = (const float*)d_in[1];
  const float* g1w = (const float*)d_in[2];
  const float* g1b = (const float*)d_in[3];
  const float* fw  = (const float*)d_in[4];
  const float* fb  = (const float*)d_in[5];
  const float* hwt = (const float*)d_in[6];
  const float* hb  = (const float*)d_in[7];
  const float* gw  = (const float*)d_in[8];
  const float* bw  = (const float*)d_in[9];
  const float* outw = (const float*)d_in[10];
  const float* outb = (const float*)d_in[11];

  char* ws = (char*)d_ws;
  const size_t MB_ = 1u << 20;
  float*  G1  = (float*)(ws + 0);            // 8 MB
  float*  G2p = (float*)(ws + 8 * MB_);      // 8 MB
  __bf16* QTb = (__bf16*)(ws + 16 * MB_);    // 4 MB
  __bf16* KTb = (__bf16*)(ws + 20 * MB_);    // 4 MB
  __bf16* Vb  = (__bf16*)(ws + 24 * MB_);    // 4 MB
  float*  Tf  = (float*)(ws + 16 * MB_);     // 8 MB, aliases QT/KT (dead after attn)
  float2* mom  = (float2*)(ws + 28 * MB_);            // 8 KB
  float2* smst = (float2*)(ws + 28 * MB_ + 8192);     // 4 KB
  float*  gamma = (float*)(ws + 28 * MB_ + 16384);    // 64 KB
  float*  beta  = (float*)(ws + 28 * MB_ + 16384 + 65536);  // 64 KB

  moments_kernel<<<dim3(BB * CC, 2), 256, 0, stream>>>(content, guidance, mom);
  conv_kernel<<<dim3(HWN / 64, BB, 6), 256, 0, stream>>>(
      content, guidance, G1, g1w, g1b, fw, fb, hwt, hb, outw, mom,
      G1, Tf, QTb, KTb, Vb, 0);
  attn_kernel<<<dim3(256), 512, 0, stream>>>(QTb, KTb, Vb, G2p);
  smstats_kernel<<<dim3(BB * CC), 256, 0, stream>>>(G2p, smst);
  gammabeta_kernel<<<dim3(HWN / 64, BB), 256, 0, stream>>>(G2p, smst, gw, bw, gamma, beta);
  conv_kernel<<<dim3(HWN / 64, BB, 2), 256, 0, stream>>>(
      content, guidance, G1, g1w, g1b, fw, fb, hwt, hb, outw, mom,
      G1, Tf, QTb, KTb, Vb, 6);
  final_kernel<<<dim3(CC, BB), 256, 0, stream>>>(Tf, gamma, beta, outw, outb, (float*)d_out);
}